// Round 2
// baseline (2310.713 us; speedup 1.0000x reference)
//
#include <hip/hip_runtime.h>
#include <hip/hip_bf16.h>
#include <stdint.h>

// ============================================================================
// ChebNet (B=16, N=8192, F=32, K=5) + MLP head.
// Round 2: dtype-agnostic ingestion (device-side fp32-vs-bf16 probe), simple
// register-staged LDS GEMM (padded rows, no swizzle/global_load_lds) to
// minimize unverified machinery. Internal states bf16 (transposed Tt[col][n]),
// partials/accumulators fp32.
// ============================================================================

#define NND 8192

typedef __bf16 bf16x8_t __attribute__((ext_vector_type(8)));
typedef float f32x4_t __attribute__((ext_vector_type(4)));

__device__ __forceinline__ float bf2f(ushort u) {
    union { unsigned int i; float f; } v; v.i = ((unsigned int)u) << 16; return v.f;
}
__device__ __forceinline__ ushort f2bf(float f) {
    union { float f; unsigned int u; } in; in.f = f;
    unsigned int u = in.u;
    unsigned int r = (u + 0x7fffu + ((u >> 16) & 1u)) >> 16;   // RNE
    return (ushort)r;
}
// dtype-agnostic scalar load: fp32 ? float : bf16
__device__ __forceinline__ float loadv(const void* p, size_t i, bool fp32) {
    return fp32 ? ((const float*)p)[i] : bf2f(((const ushort*)p)[i]);
}

// ---------------------------------------------------------------------------
// dtype probe: fp32 data viewed as ushorts has ~43% wild bf16 exponents in the
// low-mantissa halves; genuine bf16 of N(0,~0.01) data has none >= 0x93.
// ---------------------------------------------------------------------------
__global__ void detect_kernel(const ushort* __restrict__ a_raw, int* __restrict__ flag) {
    int t = threadIdx.x;      // 256 threads, sample 1024 ushorts
    int cnt = 0;
    for (int i = 0; i < 4; ++i) {
        ushort u = a_raw[t * 4 + i];
        int e = (u >> 7) & 0xff;
        if (e >= 0x93) cnt++;
    }
    if (cnt) atomicAdd(flag, cnt);
}
#define IS_FP32(flagp) ((*(flagp)) > 16)

// ---------------------------------------------------------------------------
// A (fp32 or bf16) -> canonical bf16 Abf [8192][8192]
// ---------------------------------------------------------------------------
__global__ void conv_a_kernel(const void* __restrict__ a, const int* __restrict__ flag,
                              ushort* __restrict__ Abf) {
    const bool fp32 = IS_FP32(flag);
    size_t i = (size_t)blockIdx.x * 256 + threadIdx.x;   // 4 elems per thread
    if (fp32) {
        float4 v = ((const float4*)a)[i];
        ushort4 o;
        o.x = f2bf(v.x); o.y = f2bf(v.y); o.z = f2bf(v.z); o.w = f2bf(v.w);
        ((ushort4*)Abf)[i] = o;
    } else {
        ((ushort4*)Abf)[i] = ((const ushort4*)a)[i];
    }
}

// ---------------------------------------------------------------------------
// x [16][8192][2] -> T0t [32][8192] bf16   (col c = b*2+f)
// ---------------------------------------------------------------------------
__global__ void pack_x_kernel(const void* __restrict__ x, const int* __restrict__ flag,
                              ushort* __restrict__ t0) {
    const bool fp32 = IS_FP32(flag);
    int id = blockIdx.x * 256 + threadIdx.x;     // 32*8192 ids
    int c = id >> 13, n = id & 8191;
    size_t src = ((size_t)(c >> 1) * NND + n) * 2 + (c & 1);
    t0[(size_t)c * NND + n] = f2bf(loadv(x, src, fp32));
}

// ---------------------------------------------------------------------------
// GEMM: part[ks] = A[row-tile] @ T  (K-split, fp32 partials, transposed out)
// Simple register-staged LDS, +8 ushort row pad (2-way LDS conflicts = free).
// ---------------------------------------------------------------------------
template<int BN, int S>
__global__ __launch_bounds__(256, 2) void cheb_gemm(const ushort* __restrict__ A,
                                                    const ushort* __restrict__ T,
                                                    float* __restrict__ part) {
    constexpr int CT   = (BN == 128) ? 4 : 1;     // col tiles in grid
    constexpr int COLS = BN * CT;
    constexpr int KT   = NND / S / 64;            // 64-wide K steps per block
    constexpr int WGM  = (BN == 128) ? 2 : 4;
    constexpr int WGN  = 4 / WGM;
    constexpr int WTM  = 128 / WGM;
    constexpr int WTN  = BN / WGN;
    constexpr int MI   = WTM / 16;
    constexpr int NI   = WTN / 16;
    constexpr int LDA  = 72;                      // padded row, ushorts

    __shared__ __align__(16) ushort As[128 * LDA];
    __shared__ __align__(16) ushort Bs[BN * LDA];

    const int t  = threadIdx.x;
    const int w  = t >> 6;
    const int l  = t & 63;
    const int q  = l >> 4;
    const int ln = l & 15;
    const int wm = (WGN == 2) ? (w >> 1) : w;
    const int wn = (WGN == 2) ? (w & 1) : 0;

    const int bx  = blockIdx.x;
    const int rt  = bx / (CT * S);
    const int rem = bx % (CT * S);
    const int ct  = rem / S;
    const int ks  = rem % S;
    const int kbase = ks * (NND / S);

    const ushort* Abase = A + (size_t)rt * 128 * NND + kbase;
    const ushort* Bbase = T + (size_t)ct * BN * NND + kbase;

    f32x4_t acc[MI][NI];
#pragma unroll
    for (int i = 0; i < MI; ++i)
#pragma unroll
        for (int j = 0; j < NI; ++j) acc[i][j] = (f32x4_t){0.f, 0.f, 0.f, 0.f};

    for (int kt = 0; kt < KT; ++kt) {
        const int k0 = kt * 64;
#pragma unroll
        for (int i = 0; i < 4; ++i) {                       // A tile: 128x64
            int p = i * 256 + t, m = p >> 3, c = (p & 7) * 8;
            *(uint4*)&As[m * LDA + c] = *(const uint4*)(Abase + (size_t)m * NND + k0 + c);
        }
#pragma unroll
        for (int i = 0; i < (BN * 8) / 256; ++i) {          // B tile: BNx64
            int p = i * 256 + t, m = p >> 3, c = (p & 7) * 8;
            *(uint4*)&Bs[m * LDA + c] = *(const uint4*)(Bbase + (size_t)m * NND + k0 + c);
        }
        __syncthreads();
#pragma unroll
        for (int kk = 0; kk < 2; ++kk) {
            bf16x8_t af[MI], bfr[NI];
#pragma unroll
            for (int i = 0; i < MI; ++i) {
                int m = wm * WTM + i * 16 + ln;
                af[i] = *(const bf16x8_t*)(&As[m * LDA + (kk * 4 + q) * 8]);
            }
#pragma unroll
            for (int j = 0; j < NI; ++j) {
                int n = wn * WTN + j * 16 + ln;
                bfr[j] = *(const bf16x8_t*)(&Bs[n * LDA + (kk * 4 + q) * 8]);
            }
#pragma unroll
            for (int i = 0; i < MI; ++i)
#pragma unroll
                for (int j = 0; j < NI; ++j)
                    acc[i][j] = __builtin_amdgcn_mfma_f32_16x16x32_bf16(af[i], bfr[j], acc[i][j], 0, 0, 0);
        }
        __syncthreads();
    }
    // epilogue: part[col][node] fp32, 4 consecutive nodes per lane
#pragma unroll
    for (int i = 0; i < MI; ++i) {
        int r_loc = wm * WTM + i * 16 + q * 4;
#pragma unroll
        for (int j = 0; j < NI; ++j) {
            int n_loc = wn * WTN + j * 16 + ln;
            size_t off = ((size_t)(ks * COLS + ct * BN + n_loc)) * NND + (size_t)rt * 128 + r_loc;
            float4 v;
            v.x = acc[i][j][0]; v.y = acc[i][j][1]; v.z = acc[i][j][2]; v.w = acc[i][j][3];
            *reinterpret_cast<float4*>(&part[off]) = v;
        }
    }
}

// ---------------------------------------------------------------------------
// T_next = alpha * (sum of S partials) - (use_prev ? T_prev : 0) -> bf16
// ---------------------------------------------------------------------------
template<int S>
__global__ void cheb_combine(const float* __restrict__ part, const ushort* __restrict__ Tprev,
                             ushort* __restrict__ Tnext, float alpha, int use_prev, int nelem) {
    int i4 = (blockIdx.x * 256 + threadIdx.x) * 4;
    float4 s = *(const float4*)(part + i4);
#pragma unroll
    for (int sp = 1; sp < S; ++sp) {
        float4 p = *(const float4*)(part + (size_t)sp * nelem + i4);
        s.x += p.x; s.y += p.y; s.z += p.z; s.w += p.w;
    }
    float4 v = make_float4(alpha * s.x, alpha * s.y, alpha * s.z, alpha * s.w);
    if (use_prev) {
        ushort4 u = *(const ushort4*)(Tprev + i4);
        v.x -= bf2f(u.x); v.y -= bf2f(u.y); v.z -= bf2f(u.z); v.w -= bf2f(u.w);
    }
    ushort4 o;
    o.x = f2bf(v.x); o.y = f2bf(v.y); o.z = f2bf(v.z); o.w = f2bf(v.w);
    *(ushort4*)(Tnext + i4) = o;
}

// ---------------------------------------------------------------------------
// Projection: Hout[b*32+c][n] = relu(bias[c] + sum_k sum_f w[k][f][c]*Tk[b*FI+f][n])
// ---------------------------------------------------------------------------
template<int FI>
__global__ __launch_bounds__(256) void proj_kernel(const ushort* __restrict__ Tb,
                                                   const void* __restrict__ wmat,
                                                   const void* __restrict__ bias,
                                                   const int* __restrict__ flag,
                                                   ushort* __restrict__ Hout, size_t tstride) {
    const bool fp32 = IS_FP32(flag);
    __shared__ float wf[5 * FI * 32];
    __shared__ float bfs[32];
    const int t = threadIdx.x;
    for (int i = t; i < 5 * FI * 32; i += 256) wf[i] = loadv(wmat, i, fp32);
    if (t < 32) bfs[t] = loadv(bias, t, fp32);
    __syncthreads();

    const int b = blockIdx.x >> 4;
    const int n0 = (blockIdx.x & 15) * 512 + t * 2;

    float2 acc[32];
#pragma unroll
    for (int c = 0; c < 32; ++c) acc[c] = make_float2(bfs[c], bfs[c]);

    for (int k = 0; k < 5; ++k)
        for (int f = 0; f < FI; ++f) {
            unsigned int vv = *(const unsigned int*)(&Tb[(size_t)k * tstride + (size_t)(b * FI + f) * NND + n0]);
            float v0 = bf2f((ushort)(vv & 0xffff));
            float v1 = bf2f((ushort)(vv >> 16));
            const float* wrow = &wf[(k * FI + f) * 32];
#pragma unroll
            for (int c4 = 0; c4 < 8; ++c4) {
                float4 wv = *(const float4*)(&wrow[c4 * 4]);
                acc[c4*4+0].x += wv.x * v0; acc[c4*4+0].y += wv.x * v1;
                acc[c4*4+1].x += wv.y * v0; acc[c4*4+1].y += wv.y * v1;
                acc[c4*4+2].x += wv.z * v0; acc[c4*4+2].y += wv.z * v1;
                acc[c4*4+3].x += wv.w * v0; acc[c4*4+3].y += wv.w * v1;
            }
        }
#pragma unroll
    for (int c = 0; c < 32; ++c) {
        float r0 = fmaxf(acc[c].x, 0.f), r1 = fmaxf(acc[c].y, 0.f);
        unsigned int o = (unsigned int)f2bf(r0) | ((unsigned int)f2bf(r1) << 16);
        *(unsigned int*)(&Hout[(size_t)(b * 32 + c) * NND + n0]) = o;
    }
}

// ---------------------------------------------------------------------------
// fc1: y1[b][m] += sum_k h[b][k]*fw1[k][m];  h[b][n*32+c] = h2t[b*32+c][n]
// ---------------------------------------------------------------------------
__device__ __forceinline__ void fc1_acc(float w0, float w1v, const float* hrow, float2* acc) {
    const float4* hp = (const float4*)hrow;
#pragma unroll
    for (int b4 = 0; b4 < 4; ++b4) {
        float4 hb = hp[b4];
        acc[b4*4+0].x += hb.x * w0; acc[b4*4+0].y += hb.x * w1v;
        acc[b4*4+1].x += hb.y * w0; acc[b4*4+1].y += hb.y * w1v;
        acc[b4*4+2].x += hb.z * w0; acc[b4*4+2].y += hb.z * w1v;
        acc[b4*4+3].x += hb.w * w0; acc[b4*4+3].y += hb.w * w1v;
    }
}

__global__ __launch_bounds__(256) void fc1_kernel(const ushort* __restrict__ h2t,
                                                  const void* __restrict__ fw1,
                                                  const int* __restrict__ flag,
                                                  float* __restrict__ y1) {
    const bool fp32 = IS_FP32(flag);
    __shared__ __align__(16) float hl[256][16];
    const int t = threadIdx.x;
    const int k0 = blockIdx.x * 512;
    float2 acc[16];
#pragma unroll
    for (int b = 0; b < 16; ++b) acc[b] = make_float2(0.f, 0.f);

    for (int s = 0; s < 2; ++s) {
        const int kb = k0 + s * 256;
        if (s) __syncthreads();
#pragma unroll
        for (int i = 0; i < 16; ++i) {
            int idx = i * 256 + t;
            int kl = idx >> 4, b = idx & 15;
            int k = kb + kl;
            hl[kl][b] = bf2f(h2t[(size_t)((b << 5) + (k & 31)) * NND + (k >> 5)]);
        }
        __syncthreads();
        if (fp32) {
            const float* W = (const float*)fw1;
            for (int kl = 0; kl < 256; ++kl) {
                float2 wv = *(const float2*)(W + (size_t)(kb + kl) * 512 + 2 * t);
                fc1_acc(wv.x, wv.y, hl[kl], acc);
            }
        } else {
            const ushort* W = (const ushort*)fw1;
            for (int kl = 0; kl < 256; ++kl) {
                unsigned int wp = *(const unsigned int*)(W + (size_t)(kb + kl) * 512 + 2 * t);
                fc1_acc(bf2f((ushort)(wp & 0xffff)), bf2f((ushort)(wp >> 16)), hl[kl], acc);
            }
        }
    }
#pragma unroll
    for (int b = 0; b < 16; ++b) {
        atomicAdd(&y1[b * 512 + 2 * t],     acc[b].x);
        atomicAdd(&y1[b * 512 + 2 * t + 1], acc[b].y);
    }
}

// ---------------------------------------------------------------------------
__global__ void fc2_kernel(const float* __restrict__ y1, const void* __restrict__ fb1,
                           const void* __restrict__ fw2, const void* __restrict__ fb2,
                           const int* __restrict__ flag, float* __restrict__ y2) {
    const bool fp32 = IS_FP32(flag);
    const int b = blockIdx.x, m = threadIdx.x;   // 16 blocks x 128 threads
    float acc = loadv(fb2, m, fp32);
    for (int j = 0; j < 512; ++j) {
        float v = fmaxf(y1[b * 512 + j] + loadv(fb1, j, fp32), 0.f);
        acc += v * loadv(fw2, (size_t)j * 128 + m, fp32);
    }
    y2[b * 128 + m] = fmaxf(acc, 0.f);
}

__global__ void fc3_kernel(const float* __restrict__ y2, const void* __restrict__ fw3,
                           const void* __restrict__ fb3, const int* __restrict__ flag,
                           void* __restrict__ out) {
    const bool fp32 = IS_FP32(flag);
    const int t = threadIdx.x;
    if (t < 16) {
        float l0 = loadv(fb3, 0, fp32), l1 = loadv(fb3, 1, fp32);
        for (int j = 0; j < 128; ++j) {
            float v = y2[t * 128 + j];
            l0 += v * loadv(fw3, (size_t)j * 2,     fp32);
            l1 += v * loadv(fw3, (size_t)j * 2 + 1, fp32);
        }
        float mx = fmaxf(l0, l1);
        float e0 = __expf(l0 - mx), e1 = __expf(l1 - mx);
        float inv = 1.f / (e0 + e1);
        if (fp32) {
            ((float*)out)[t * 2]     = e0 * inv;
            ((float*)out)[t * 2 + 1] = e1 * inv;
        } else {
            ((ushort*)out)[t * 2]     = f2bf(e0 * inv);
            ((ushort*)out)[t * 2 + 1] = f2bf(e1 * inv);
        }
    }
}

// ===========================================================================
extern "C" void kernel_launch(void* const* d_in, const int* in_sizes, int n_in,
                              void* d_out, int out_size, void* d_ws, size_t ws_size,
                              hipStream_t stream) {
    const void* x   = d_in[0];
    const void* a   = d_in[1];
    const void* w1  = d_in[2];
    const void* b1  = d_in[3];
    const void* w2  = d_in[4];
    const void* b2  = d_in[5];
    const void* fw1 = d_in[6];
    const void* fb1 = d_in[7];
    const void* fw2 = d_in[8];
    const void* fb2 = d_in[9];
    const void* fw3 = d_in[10];
    const void* fb3 = d_in[11];

    const size_t T2E = (size_t)512 * NND;   // conv2 state elems
    const size_t T1E = (size_t)32 * NND;    // conv1 state elems
    const size_t AE  = (size_t)NND * NND;   // 67.1M

    int*    flag = (int*)d_ws;
    ushort* Abf  = (ushort*)d_ws + 8;           // 16B-aligned
    ushort* T2   = Abf + AE;                    // 5 * T2E bf16
    ushort* h2t  = T2 + 5 * T2E;                // T2E bf16
    ushort* T1   = h2t + T2E;                   // 5 * T1E bf16
    float*  part = (float*)(T1 + 5 * T1E);      // 2*T2E floats (fits 4*T1E too)
    float*  y1   = part + 2 * T2E;              // 16*512
    float*  y2   = y1 + 16 * 512;               // 16*128

    hipMemsetAsync(flag, 0, sizeof(int), stream);
    detect_kernel<<<1, 256, 0, stream>>>((const ushort*)a, flag);
    conv_a_kernel<<<(int)(AE / 4 / 256), 256, 0, stream>>>(a, flag, Abf);
    pack_x_kernel<<<1024, 256, 0, stream>>>(x, flag, T1);

    // conv1: K-split 4 over 32 cols
    for (int k = 1; k <= 4; ++k) {
        cheb_gemm<32, 4><<<256, 256, 0, stream>>>(Abf, T1 + (size_t)(k - 1) * T1E, part);
        cheb_combine<4><<<256, 256, 0, stream>>>(part,
            (k >= 2) ? (T1 + (size_t)(k - 2) * T1E) : nullptr,
            T1 + (size_t)k * T1E, (k == 1) ? 1.f : 2.f, (k >= 2) ? 1 : 0, (int)T1E);
    }
    proj_kernel<2><<<256, 256, 0, stream>>>(T1, w1, b1, flag, T2, T1E);

    // conv2: K-split 2 over 512 cols
    for (int k = 1; k <= 4; ++k) {
        cheb_gemm<128, 2><<<512, 256, 0, stream>>>(Abf, T2 + (size_t)(k - 1) * T2E, part);
        cheb_combine<2><<<4096, 256, 0, stream>>>(part,
            (k >= 2) ? (T2 + (size_t)(k - 2) * T2E) : nullptr,
            T2 + (size_t)k * T2E, (k == 1) ? 1.f : 2.f, (k >= 2) ? 1 : 0, (int)T2E);
    }
    proj_kernel<32><<<256, 256, 0, stream>>>(T2, w2, b2, flag, h2t, T2E);

    hipMemsetAsync(y1, 0, 16 * 512 * sizeof(float), stream);
    fc1_kernel<<<512, 256, 0, stream>>>(h2t, fw1, flag, y1);
    fc2_kernel<<<16, 128, 0, stream>>>(y1, fb1, fw2, fb2, flag, y2);
    fc3_kernel<<<1, 64, 0, stream>>>(y2, fw3, fb3, flag, (void*)d_out);
}